// Round 11
// baseline (194.660 us; speedup 1.0000x reference)
//
#include <hip/hip_runtime.h>

// VolSDF volume rendering — persistent double-buffered streamer.
// History: r3 (1 ray/wave, float2) 60-62us; r5 (4 rays/wave, float4, strided
// color) 63us; r10 (LDS-staged coalesced color) 63.5us. Structure-invariant
// time with nothing saturated (HBM 16%, VALU 11%) => testing the burst-MLP
// hypothesis: waves issue one load burst then go quiet. This version keeps
// load issue continuously active: each wave owns 16 rays in 8 groups of 2,
// register-double-buffered (prefetch group g+1 while computing group g).
//   - 2 rays/group: lanes 0-31 ray A, lanes 32-63 ray B, 4 points/lane.
//   - 5 dwordx4 loads per group per lane (dist, depth, 3x color).
//   - FAR_DELTA sentinel kept OUT of the scan (f32 ulp at 1e11 ~ 8192 ->
//     catastrophic cancellation).

#define ALPHA_C    10.0f
#define INV_BETA   20.0f      // 1 / 0.05
#define FAR_DELTA  1.0e10f
#define N_PTS      128
#define GROUPS     8          // ray-groups per wave (2 rays each)

struct Buf { float4 d, z, c0, c1, c2; };

__device__ __forceinline__ float sdf_density(float dist) {
    float sd = -dist;
    // Laplace CDF: sd<=0 -> 0.5*exp(sd/beta); else 1 - 0.5*exp(-sd/beta)
    float e  = __expf(-fabsf(sd) * INV_BETA);
    return (sd <= 0.0f) ? (ALPHA_C * 0.5f * e)
                        : (ALPHA_C * (1.0f - 0.5f * e));
}

__device__ __forceinline__ void load_group(Buf& B,
    const float4* __restrict__ dist4, const float4* __restrict__ depth4,
    const float4* __restrict__ col4, int ray, int i)
{
    B.d = dist4 [(size_t)ray * 32 + i];
    B.z = depth4[(size_t)ray * 32 + i];
    const float4* c = col4 + (size_t)ray * 96 + 3 * i;
    B.c0 = c[0];   // r0 g0 b0 r1
    B.c1 = c[1];   // g1 b1 r2 g2
    B.c2 = c[2];   // b2 r3 g3 b3
}

__device__ __forceinline__ void compute_group(const Buf& B, int ray, int i,
                                              float* __restrict__ out)
{
    const float4 z = B.z, d = B.d;

    // deltas: 3 in-register, last needs next lane's z.x
    float zn  = __shfl_down(z.x, 1, 32);
    float dd0 = sdf_density(d.x) * (z.y - z.x);
    float dd1 = sdf_density(d.y) * (z.z - z.y);
    float dd2 = sdf_density(d.z) * (z.w - z.z);
    float dd3 = sdf_density(d.w) * ((i == 31) ? FAR_DELTA : (zn - z.w));

    // exclusive prefix over this half's 128 points (sentinel excluded)
    float s = dd0 + dd1 + dd2 + ((i == 31) ? 0.0f : dd3);
    float incl = s;
    #pragma unroll
    for (int off = 1; off < 32; off <<= 1) {
        float v = __shfl_up(incl, off, 32);
        if (i >= off) incl += v;
    }
    float excl = incl - s;               // sum of dd_j, j < 4i

    float p1 = excl + dd0;
    float p2 = p1 + dd1;
    float p3 = p2 + dd2;
    float w0 = __expf(-excl) * (1.0f - __expf(-dd0));
    float w1 = __expf(-p1)   * (1.0f - __expf(-dd1));
    float w2 = __expf(-p2)   * (1.0f - __expf(-dd2));
    float w3 = __expf(-p3)   * (1.0f - __expf(-dd3));  // i==31: exp(-1e11)=0 -> w3=T

    float r = w0 * B.c0.x + w1 * B.c0.w + w2 * B.c1.z + w3 * B.c2.y;
    float g = w0 * B.c0.y + w1 * B.c1.x + w2 * B.c1.w + w3 * B.c2.z;
    float b = w0 * B.c0.z + w1 * B.c1.y + w2 * B.c2.x + w3 * B.c2.w;

    // half-wave tree reduction (r,g,b 3-way ILP)
    #pragma unroll
    for (int off = 16; off >= 1; off >>= 1) {
        r += __shfl_down(r, off, 32);
        g += __shfl_down(g, off, 32);
        b += __shfl_down(b, off, 32);
    }
    if (i == 0) {
        float* o = out + (size_t)ray * 3;
        o[0] = r; o[1] = g; o[2] = b;
    }
}

__global__ __launch_bounds__(256) void volsdf_render_kernel(
    const float4* __restrict__ dist4,    // 32 float4 per ray
    const float4* __restrict__ depth4,   // 32 float4 per ray
    const float4* __restrict__ col4,     // 96 float4 per ray
    float* __restrict__ out)
{
    const int tid  = (int)threadIdx.x;
    const int wv   = tid >> 6;            // wave within block: 0..3
    const int lane = tid & 63;
    const int half = lane >> 5;           // which ray of the pair
    const int i    = lane & 31;           // position within the 32-lane half

    // global wave id; each wave owns 16 consecutive rays (8 groups of 2)
    const int ray_base = ((int)blockIdx.x * 4 + wv) * (2 * GROUPS);

    Buf A, B;
    load_group(A, dist4, depth4, col4, ray_base + half, i);

    // static ping-pong (compile-time buffer selection via full unroll)
    #pragma unroll
    for (int g = 0; g < GROUPS; ++g) {
        const int ray = ray_base + 2 * g + half;
        if ((g & 1) == 0) {
            if (g < GROUPS - 1)
                load_group(B, dist4, depth4, col4, ray_base + 2 * (g + 1) + half, i);
            compute_group(A, ray, i, out);
        } else {
            if (g < GROUPS - 1)
                load_group(A, dist4, depth4, col4, ray_base + 2 * (g + 1) + half, i);
            compute_group(B, ray, i, out);
        }
    }
}

extern "C" void kernel_launch(void* const* d_in, const int* in_sizes, int n_in,
                              void* d_out, int out_size, void* d_ws, size_t ws_size,
                              hipStream_t stream) {
    const float4* dist4  = (const float4*)d_in[0];
    const float4* col4   = (const float4*)d_in[1];
    const float4* depth4 = (const float4*)d_in[2];
    float* out = (float*)d_out;

    const int n_rays = in_sizes[0] / N_PTS;          // 65536
    const int rays_per_block = 4 * 2 * GROUPS;       // 4 waves x 16 rays = 64
    const int blocks = n_rays / rays_per_block;      // 1024
    volsdf_render_kernel<<<blocks, 256, 0, stream>>>(dist4, depth4, col4, out);
}